// Round 5
// baseline (1906.425 us; speedup 1.0000x reference)
//
#include <hip/hip_runtime.h>
#include <hip/hip_bf16.h>

#define T_STEPS 2048
#define BATCH   1024
#define NUNITS  128
#define ROWS    8
#define LOG2E   1.4426950408889634f

typedef __attribute__((ext_vector_type(8))) __bf16 bf16x8;
typedef __attribute__((ext_vector_type(4))) __bf16 bf16x4;
typedef __attribute__((ext_vector_type(4))) float  f32x4;

__device__ __forceinline__ float sigm_pre(float xs) {
    // xs PRE-SCALED by log2e: sigm = 1/(1+2^-xs)
    return __builtin_amdgcn_rcpf(1.0f + __builtin_amdgcn_exp2f(-xs));
}
__device__ __forceinline__ float tanh_pre(float xs) {
    // xs PRE-SCALED by 2*log2e: tanh = 1 - 2/(1+2^xs); inf-safe (rcp(inf)=0)
    return fmaf(-2.0f, __builtin_amdgcn_rcpf(1.0f + __builtin_amdgcn_exp2f(xs)), 1.0f);
}
// pull value from lane (self & ~8): identity for lanes with bit3=0, lane-8 otherwise.
// ds_bpermute is full-wave64, byte lane address — no 32-lane-group mask ambiguity.
__device__ __forceinline__ float pull8(float x, int bpa) {
    return __builtin_bit_cast(float,
        __builtin_amdgcn_ds_bpermute(bpa, __builtin_bit_cast(int, x)));
}

// ---------------- embedding pre-pass (HBM-bound)
__global__ __launch_bounds__(256) void emb_kernel(const float* __restrict__ x,
                                                  const float* __restrict__ Wemb,
                                                  const float* __restrict__ bemb,
                                                  ushort* __restrict__ e_out) {
    int g = blockIdx.x * 256 + threadIdx.x;   // g = t*1024 + b
    int t = g >> 10;
    int b = g & 1023;
    const float* xr = x + ((size_t)b * T_STEPS + t) * 64;

    float4 xv[16];
#pragma unroll
    for (int i = 0; i < 16; i++) xv[i] = ((const float4*)xr)[i];

    float acc[24];
#pragma unroll
    for (int j = 0; j < 24; j++) acc[j] = bemb[j];

#pragma unroll
    for (int d = 0; d < 64; d++) {
        float xs = ((const float*)xv)[d];
#pragma unroll
        for (int j = 0; j < 24; j++) acc[j] = fmaf(xs, Wemb[d * 24 + j], acc[j]);
    }

    uint outp[12];
#pragma unroll
    for (int p = 0; p < 12; p++) {
        float lo = __builtin_amdgcn_rcpf(1.0f + __builtin_amdgcn_exp2f(-LOG2E * acc[2 * p]));
        float hi = __builtin_amdgcn_rcpf(1.0f + __builtin_amdgcn_exp2f(-LOG2E * acc[2 * p + 1]));
        ushort ulo = __builtin_bit_cast(ushort, (__bf16)lo);
        ushort uhi = __builtin_bit_cast(ushort, (__bf16)hi);
        outp[p] = (uint)ulo | ((uint)uhi << 16);
    }
    uint4* dst = (uint4*)(e_out + (size_t)g * 24);
#pragma unroll
    for (int q = 0; q < 3; q++) dst[q] = ((const uint4*)outp)[q];
}

// ---------------- recurrent kernel: 128 blocks x 256 threads, 8 batch rows per block
// Wave wv owns units [32wv, 32wv+32) as 2 M-tiles. A = W (regs), B = z (LDS),
// D[m=unit][n=row]: lane(kg,l15) reg r -> unit tilebase+kg*4+r, row l15 (valid l15<8).
// Compaction: hi lanes (l15>=8) take tile1's regs from lane (lane-8) via ds_bpermute.
__global__ __launch_bounds__(256, 1) void lstm_kernel(
    const ushort* __restrict__ e_ws,
    const float* __restrict__ Wf, const float* __restrict__ bf_,
    const float* __restrict__ Wi, const float* __restrict__ bi_,
    const float* __restrict__ Wg, const float* __restrict__ bg_,
    const float* __restrict__ Wo, const float* __restrict__ bo_,
    const float* __restrict__ Wout, const float* __restrict__ bout,
    float* __restrict__ out) {
    __shared__ __align__(16) __bf16 zfrag[2][4][4][16][8];   // [P][ks][kslot][row][8] = 8 KiB

    const int tid  = threadIdx.x;
    const int lane = tid & 63;
    const int wv   = tid >> 6;      // 0..3
    const int l15  = lane & 15;
    const int kg   = lane >> 4;     // 0..3
    const int r0   = blockIdx.x * ROWS;
    const bool lo8 = (l15 < 8);
    const int bpa  = (lane & ~8) << 2;   // bpermute byte addr: self for lo, lane-8 for hi

    // ---- persistent W fragments: wreg[tile][gate][ks], pre-scaled by exp2 constants
    const float* Wp[4] = {Wf, Wi, Wg, Wo};
    const float gsc[4] = {LOG2E, LOG2E, 2.0f * LOG2E, LOG2E};
    bf16x8 wreg[2][4][5];
#pragma unroll
    for (int tile = 0; tile < 2; tile++) {
        const int ucol = wv * 32 + tile * 16 + l15;
#pragma unroll
        for (int gt = 0; gt < 4; gt++) {
#pragma unroll
            for (int ks = 0; ks < 5; ks++) {
#pragma unroll
                for (int j = 0; j < 8; j++) {
                    int k = ks * 32 + kg * 8 + j;
                    float v = 0.0f;
                    if (k < 128) v = Wp[gt][(24 + k) * NUNITS + ucol];        // h rows
                    else if (k < 152) v = Wp[gt][(k - 128) * NUNITS + ucol];  // e rows
                    wreg[tile][gt][ks][j] = (__bf16)(v * gsc[gt]);
                }
            }
        }
    }
    // biases (C-operand of the hoisted e-MFMA), bias[gate][tile]
    const float* Bp[4] = {bf_, bi_, bg_, bo_};
    f32x4 bias[4][2];
#pragma unroll
    for (int gt = 0; gt < 4; gt++)
#pragma unroll
        for (int tile = 0; tile < 2; tile++)
#pragma unroll
            for (int r = 0; r < 4; r++)
                bias[gt][tile][r] = Bp[gt][wv * 32 + tile * 16 + kg * 4 + r] * gsc[gt];

    // zero both z buffers (h0 = 0; rows 8-15 stay zero forever)
    for (int i = tid; i < 2 * 4 * 4 * 16 * 8; i += 256) ((__bf16*)zfrag)[i] = (__bf16)0.0f;

    // LDS addresses (elements); [P] stride = 2048, [ks] stride = 512
    const __bf16* zrd = &zfrag[0][0][kg][l15][0];
    const int kslot_w = (lo8 ? 0 : 2) + (kg >> 1);
    const int eb      = (kg & 1) * 4;
    __bf16* zwr = &zfrag[0][wv][kslot_w][l15 & 7][eb];

    // ---- e prefetch ring, depth 2 (B-frag rows l15<8, k-groups kg<3)
    const ushort* elbase = e_ws + ((size_t)(r0 + (l15 & 7)) * 24 + kg * 8);
    const bool eload = (kg < 3) && lo8;
    bf16x8 e0, e1;
#pragma unroll
    for (int j = 0; j < 8; j++) { e0[j] = (__bf16)0.0f; e1[j] = (__bf16)0.0f; }
    if (eload) {
        e0 = *(const bf16x8*)(const void*)(elbase);
        e1 = *(const bf16x8*)(const void*)(elbase + 24576);   // t=1 (1024*24/step)
    }

    __syncthreads();

    float c[4] = {0, 0, 0, 0};
    f32x4 eA[4][2], eB[4][2];   // hoisted e-acc (bias + W_e*e(t)), [gate][tile]
#pragma unroll
    for (int tile = 0; tile < 2; tile++)
#pragma unroll
        for (int gt = 0; gt < 4; gt++)
            eA[gt][tile] = __builtin_amdgcn_mfma_f32_16x16x32_bf16(wreg[tile][gt][4], e0,
                                                                   bias[gt][tile], 0, 0, 0);
    if (eload) e0 = *(const bf16x8*)(const void*)(elbase + 2 * 24576);   // e(2)

    auto STEP = [&](int t, int P, f32x4 (&cur)[4][2], f32x4 (&nxt)[4][2], bf16x8& enext) {
        const __bf16* zb = zrd + P * 2048;
        bf16x8 z0 = *(const bf16x8*)(const void*)(zb);
        bf16x8 z1 = *(const bf16x8*)(const void*)(zb + 512);
        bf16x8 z2 = *(const bf16x8*)(const void*)(zb + 1024);
        bf16x8 z3 = *(const bf16x8*)(const void*)(zb + 1536);

        f32x4 acc[4][2];
#pragma unroll
        for (int tile = 0; tile < 2; tile++)
#pragma unroll
            for (int gt = 0; gt < 4; gt++) {
                acc[gt][tile] = __builtin_amdgcn_mfma_f32_16x16x32_bf16(wreg[tile][gt][0], z0, cur[gt][tile], 0, 0, 0);
                acc[gt][tile] = __builtin_amdgcn_mfma_f32_16x16x32_bf16(wreg[tile][gt][1], z1, acc[gt][tile], 0, 0, 0);
                acc[gt][tile] = __builtin_amdgcn_mfma_f32_16x16x32_bf16(wreg[tile][gt][2], z2, acc[gt][tile], 0, 0, 0);
                acc[gt][tile] = __builtin_amdgcn_mfma_f32_16x16x32_bf16(wreg[tile][gt][3], z3, acc[gt][tile], 0, 0, 0);
            }

        // hoisted e-MFMAs for step t+1 (independent of h)
#pragma unroll
        for (int tile = 0; tile < 2; tile++)
#pragma unroll
            for (int gt = 0; gt < 4; gt++)
                nxt[gt][tile] = __builtin_amdgcn_mfma_f32_16x16x32_bf16(wreg[tile][gt][4], enext,
                                                                        bias[gt][tile], 0, 0, 0);
        // refill enext with e(t+3), clamped
        {
            int tf = t + 3; if (tf > T_STEPS - 1) tf = T_STEPS - 1;
            if (eload) enext = *(const bf16x8*)(const void*)(elbase + (size_t)tf * 24576);
        }

        // compaction: lo lanes keep tile0; hi lanes pull tile1 from lane-8.
        // bpermute computed UNCONDITIONALLY (full exec), then per-lane select.
        f32x4 gF, gI, gG, gO;
#pragma unroll
        for (int r = 0; r < 4; r++) {
            float pF = pull8(acc[0][1][r], bpa);
            float pI = pull8(acc[1][1][r], bpa);
            float pG = pull8(acc[2][1][r], bpa);
            float pO = pull8(acc[3][1][r], bpa);
            gF[r] = lo8 ? acc[0][0][r] : pF;
            gI[r] = lo8 ? acc[1][0][r] : pI;
            gG[r] = lo8 ? acc[2][0][r] : pG;
            gO[r] = lo8 ? acc[3][0][r] : pO;
        }

        bf16x4 hp;
#pragma unroll
        for (int r = 0; r < 4; r++) {
            float fg = sigm_pre(gF[r]);
            float ig = sigm_pre(gI[r]);
            float gg = tanh_pre(gG[r]);
            float og = sigm_pre(gO[r]);
            c[r] = fmaf(c[r], fg, ig * gg);
            hp[r] = (__bf16)(tanh_pre(2.0f * LOG2E * c[r]) * og);
        }
        *(bf16x4*)(zwr + (P ^ 1) * 2048) = hp;

        // LDS-only drain + raw barrier: vmem e-prefetch stays in flight
        asm volatile("s_waitcnt lgkmcnt(0)" ::: "memory");
        __builtin_amdgcn_s_barrier();
        __builtin_amdgcn_sched_barrier(0);
    };

    for (int t = 0; t < T_STEPS; t += 2) {
        STEP(t,     0, eA, eB, e1);
        STEP(t + 1, 1, eB, eA, e0);
    }

    // h_last is in buffer 0
    if (tid < ROWS) {
        float s = bout[0];
#pragma unroll
        for (int k = 0; k < NUNITS; k++)
            s += (float)zfrag[0][k >> 5][(k >> 3) & 3][tid][k & 7] * Wout[k];
        out[r0 + tid] = __builtin_amdgcn_rcpf(1.0f + __builtin_amdgcn_exp2f(-LOG2E * s));
    }
}

extern "C" void kernel_launch(void* const* d_in, const int* in_sizes, int n_in,
                              void* d_out, int out_size, void* d_ws, size_t ws_size,
                              hipStream_t stream) {
    const float* x     = (const float*)d_in[0];
    const float* Wemb  = (const float*)d_in[1];
    const float* bemb  = (const float*)d_in[2];
    const float* Wf    = (const float*)d_in[3];
    const float* bf_   = (const float*)d_in[4];
    const float* Wi    = (const float*)d_in[5];
    const float* bi_   = (const float*)d_in[6];
    const float* Wg    = (const float*)d_in[7];
    const float* bg_   = (const float*)d_in[8];
    const float* Wo    = (const float*)d_in[9];
    const float* bo_   = (const float*)d_in[10];
    const float* Wout  = (const float*)d_in[11];
    const float* bout  = (const float*)d_in[12];
    float* out = (float*)d_out;
    ushort* e_ws = (ushort*)d_ws;   // [T][B][24] bf16, ~96 MB

    int nrows = BATCH * T_STEPS;
    emb_kernel<<<nrows / 256, 256, 0, stream>>>(x, Wemb, bemb, e_ws);
    lstm_kernel<<<BATCH / ROWS, 256, 0, stream>>>(e_ws, Wf, bf_, Wi, bi_, Wg, bg_,
                                                  Wo, bo_, Wout, bout, out);
}

// Round 6
// 1459.212 us; speedup vs baseline: 1.3065x; 1.3065x over previous
//
#include <hip/hip_runtime.h>
#include <hip/hip_bf16.h>

#define T_STEPS 2048
#define BATCH   1024
#define NUNITS  128
#define ROWS    8
#define LOG2E   1.4426950408889634f

typedef __attribute__((ext_vector_type(8))) __bf16 bf16x8;
typedef __attribute__((ext_vector_type(4))) float  f32x4;

__device__ __forceinline__ float sigm_pre(float xs) {
    // xs PRE-SCALED by log2e: sigm = 1/(1+2^-xs)
    return __builtin_amdgcn_rcpf(1.0f + __builtin_amdgcn_exp2f(-xs));
}
__device__ __forceinline__ float tanh_pre(float xs) {
    // xs PRE-SCALED by 2*log2e: tanh = 1 - 2/(1+2^xs); inf-safe (rcp(inf)=0)
    return fmaf(-2.0f, __builtin_amdgcn_rcpf(1.0f + __builtin_amdgcn_exp2f(xs)), 1.0f);
}
// pull value from lane (self & ~8): identity for lanes with bit3=0, lane-8 otherwise
__device__ __forceinline__ float pull8(float x, int bpa) {
    return __builtin_bit_cast(float,
        __builtin_amdgcn_ds_bpermute(bpa, __builtin_bit_cast(int, x)));
}

// ---------------- embedding pre-pass (HBM-bound)
__global__ __launch_bounds__(256) void emb_kernel(const float* __restrict__ x,
                                                  const float* __restrict__ Wemb,
                                                  const float* __restrict__ bemb,
                                                  ushort* __restrict__ e_out) {
    int g = blockIdx.x * 256 + threadIdx.x;   // g = t*1024 + b
    int t = g >> 10;
    int b = g & 1023;
    const float* xr = x + ((size_t)b * T_STEPS + t) * 64;

    float4 xv[16];
#pragma unroll
    for (int i = 0; i < 16; i++) xv[i] = ((const float4*)xr)[i];

    float acc[24];
#pragma unroll
    for (int j = 0; j < 24; j++) acc[j] = bemb[j];

#pragma unroll
    for (int d = 0; d < 64; d++) {
        float xs = ((const float*)xv)[d];
#pragma unroll
        for (int j = 0; j < 24; j++) acc[j] = fmaf(xs, Wemb[d * 24 + j], acc[j]);
    }

    uint outp[12];
#pragma unroll
    for (int p = 0; p < 12; p++) {
        float lo = __builtin_amdgcn_rcpf(1.0f + __builtin_amdgcn_exp2f(-LOG2E * acc[2 * p]));
        float hi = __builtin_amdgcn_rcpf(1.0f + __builtin_amdgcn_exp2f(-LOG2E * acc[2 * p + 1]));
        ushort ulo = __builtin_bit_cast(ushort, (__bf16)lo);
        ushort uhi = __builtin_bit_cast(ushort, (__bf16)hi);
        outp[p] = (uint)ulo | ((uint)uhi << 16);
    }
    uint4* dst = (uint4*)(e_out + (size_t)g * 24);
#pragma unroll
    for (int q = 0; q < 3; q++) dst[q] = ((const uint4*)outp)[q];
}

// ---------------- recurrent kernel: 128 blocks x 512 threads (8 waves), 8 rows/block
// Wave wv owns ONE 16-unit tile [16wv,16wv+16). A = W (regs), B = z (LDS),
// D[m=unit][n=row]: lane(kg,l15) reg r -> unit 16wv+kg*4+r, row l15 (valid l15<8).
// Compaction-2: lo lanes keep regs{0,1}; hi lanes pull regs{2,3} from lane-8.
// Each thread then owns 2 cells -> 20 trans/step (the 128-CU trans floor),
// with 2 waves/SIMD for latency overlap (R5 post-mortem: 1 wave/SIMD exposed ~1260cyc).
__global__ __launch_bounds__(512, 1) void lstm_kernel(
    const ushort* __restrict__ e_ws,
    const float* __restrict__ Wf, const float* __restrict__ bf_,
    const float* __restrict__ Wi, const float* __restrict__ bi_,
    const float* __restrict__ Wg, const float* __restrict__ bg_,
    const float* __restrict__ Wo, const float* __restrict__ bo_,
    const float* __restrict__ Wout, const float* __restrict__ bout,
    float* __restrict__ out) {
    __shared__ __align__(16) __bf16 zfrag[2][4][4][16][8];   // [P][ks][kslot][row16][8] = 8 KiB

    const int tid  = threadIdx.x;
    const int lane = tid & 63;
    const int wv   = tid >> 6;      // 0..7 -> unit tile [16wv,16wv+16)
    const int l15  = lane & 15;
    const int kg   = lane >> 4;     // 0..3
    const int r0   = blockIdx.x * ROWS;
    const bool lo8 = (l15 < 8);
    const int bpa  = (lane & ~8) << 2;   // bpermute byte addr

    // ---- persistent W fragments wreg[gate][ks], pre-scaled by exp2 constants
    const float* Wp[4] = {Wf, Wi, Wg, Wo};
    const float gsc[4] = {LOG2E, LOG2E, 2.0f * LOG2E, LOG2E};
    const int ucol = wv * 16 + l15;
    bf16x8 wreg[4][5];
#pragma unroll
    for (int gt = 0; gt < 4; gt++) {
#pragma unroll
        for (int ks = 0; ks < 5; ks++) {
#pragma unroll
            for (int j = 0; j < 8; j++) {
                int k = ks * 32 + kg * 8 + j;
                float v = 0.0f;
                if (k < 128) v = Wp[gt][(24 + k) * NUNITS + ucol];        // h rows
                else if (k < 152) v = Wp[gt][(k - 128) * NUNITS + ucol];  // e rows
                wreg[gt][ks][j] = (__bf16)(v * gsc[gt]);
            }
        }
    }
    // biases (C-operand of hoisted e-MFMA) for units 16wv+kg*4+r
    const float* Bp[4] = {bf_, bi_, bg_, bo_};
    f32x4 bias[4];
#pragma unroll
    for (int gt = 0; gt < 4; gt++)
#pragma unroll
        for (int r = 0; r < 4; r++)
            bias[gt][r] = Bp[gt][wv * 16 + kg * 4 + r] * gsc[gt];

    // zero both z buffers (h0 = 0; rows 8-15 stay zero forever)
    for (int i = tid; i < 2 * 4 * 4 * 16 * 8; i += 512) ((__bf16*)zfrag)[i] = (__bf16)0.0f;

    // LDS addresses; [P] stride = 2048 elems, [ks] stride = 512
    const __bf16* zrd = &zfrag[0][0][kg][l15][0];
    // write slot: this thread's 2 compacted cells = units u0w,u0w+1, row l15&7
    const int u0w = wv * 16 + kg * 4 + (lo8 ? 0 : 2);
    __bf16* zwr = &zfrag[0][u0w >> 5][(u0w >> 3) & 3][l15 & 7][u0w & 7];

    // ---- e prefetch ring, depth 2 (rows l15<8, k-groups kg<3); dup across waves (L1-hit)
    const ushort* elbase = e_ws + ((size_t)(r0 + (l15 & 7)) * 24 + kg * 8);
    const bool eload = (kg < 3) && lo8;
    bf16x8 e0, e1;
#pragma unroll
    for (int j = 0; j < 8; j++) { e0[j] = (__bf16)0.0f; e1[j] = (__bf16)0.0f; }
    if (eload) {
        e0 = *(const bf16x8*)(const void*)(elbase);
        e1 = *(const bf16x8*)(const void*)(elbase + 24576);   // t=1
    }

    __syncthreads();

    float c0 = 0.0f, c1 = 0.0f;   // cell state for this thread's 2 compacted cells
    f32x4 eA[4], eB[4];           // hoisted e-acc (bias + W_e*e(t)) per gate
#pragma unroll
    for (int gt = 0; gt < 4; gt++)
        eA[gt] = __builtin_amdgcn_mfma_f32_16x16x32_bf16(wreg[gt][4], e0, bias[gt], 0, 0, 0);
    if (eload) e0 = *(const bf16x8*)(const void*)(elbase + 2 * 24576);   // e(2)

    auto STEP = [&](int t, int P, f32x4 (&cur)[4], f32x4 (&nxt)[4], bf16x8& enext) {
        const __bf16* zb = zrd + P * 2048;
        bf16x8 z0 = *(const bf16x8*)(const void*)(zb);
        bf16x8 z1 = *(const bf16x8*)(const void*)(zb + 512);
        bf16x8 z2 = *(const bf16x8*)(const void*)(zb + 1024);
        bf16x8 z3 = *(const bf16x8*)(const void*)(zb + 1536);

        f32x4 acc[4];
#pragma unroll
        for (int gt = 0; gt < 4; gt++) {
            acc[gt] = __builtin_amdgcn_mfma_f32_16x16x32_bf16(wreg[gt][0], z0, cur[gt], 0, 0, 0);
            acc[gt] = __builtin_amdgcn_mfma_f32_16x16x32_bf16(wreg[gt][1], z1, acc[gt], 0, 0, 0);
            acc[gt] = __builtin_amdgcn_mfma_f32_16x16x32_bf16(wreg[gt][2], z2, acc[gt], 0, 0, 0);
            acc[gt] = __builtin_amdgcn_mfma_f32_16x16x32_bf16(wreg[gt][3], z3, acc[gt], 0, 0, 0);
        }

        // hoisted e-MFMAs for step t+1 (independent of h)
#pragma unroll
        for (int gt = 0; gt < 4; gt++)
            nxt[gt] = __builtin_amdgcn_mfma_f32_16x16x32_bf16(wreg[gt][4], enext, bias[gt], 0, 0, 0);
        {
            int tf = t + 3; if (tf > T_STEPS - 1) tf = T_STEPS - 1;
            if (eload) enext = *(const bf16x8*)(const void*)(elbase + (size_t)tf * 24576);
        }

        // compaction-2: lo lanes keep regs{0,1}; hi lanes pull regs{2,3} from lane-8
        float g0[4], g1[4];
#pragma unroll
        for (int gt = 0; gt < 4; gt++) {
            float q2 = pull8(acc[gt][2], bpa);
            float q3 = pull8(acc[gt][3], bpa);
            g0[gt] = lo8 ? acc[gt][0] : q2;
            g1[gt] = lo8 ? acc[gt][1] : q3;
        }

        float fg0 = sigm_pre(g0[0]), fg1 = sigm_pre(g1[0]);
        float ig0 = sigm_pre(g0[1]), ig1 = sigm_pre(g1[1]);
        float gg0 = tanh_pre(g0[2]), gg1 = tanh_pre(g1[2]);
        float og0 = sigm_pre(g0[3]), og1 = sigm_pre(g1[3]);
        c0 = fmaf(c0, fg0, ig0 * gg0);
        c1 = fmaf(c1, fg1, ig1 * gg1);
        float h0 = tanh_pre(2.0f * LOG2E * c0) * og0;
        float h1 = tanh_pre(2.0f * LOG2E * c1) * og1;

        uint hp = (uint)__builtin_bit_cast(ushort, (__bf16)h0) |
                  ((uint)__builtin_bit_cast(ushort, (__bf16)h1) << 16);
        *(uint*)(zwr + (P ^ 1) * 2048) = hp;   // b32, 2-way bank alias = free

        // LDS-only drain + raw barrier: vmem e-prefetch stays in flight
        asm volatile("s_waitcnt lgkmcnt(0)" ::: "memory");
        __builtin_amdgcn_s_barrier();
        __builtin_amdgcn_sched_barrier(0);
    };

    for (int t = 0; t < T_STEPS; t += 2) {
        STEP(t,     0, eA, eB, e1);
        STEP(t + 1, 1, eB, eA, e0);
    }

    // h_last is in buffer 0
    if (tid < ROWS) {
        float s = bout[0];
#pragma unroll
        for (int k = 0; k < NUNITS; k++)
            s += (float)zfrag[0][k >> 5][(k >> 3) & 3][tid][k & 7] * Wout[k];
        out[r0 + tid] = __builtin_amdgcn_rcpf(1.0f + __builtin_amdgcn_exp2f(-LOG2E * s));
    }
}

extern "C" void kernel_launch(void* const* d_in, const int* in_sizes, int n_in,
                              void* d_out, int out_size, void* d_ws, size_t ws_size,
                              hipStream_t stream) {
    const float* x     = (const float*)d_in[0];
    const float* Wemb  = (const float*)d_in[1];
    const float* bemb  = (const float*)d_in[2];
    const float* Wf    = (const float*)d_in[3];
    const float* bf_   = (const float*)d_in[4];
    const float* Wi    = (const float*)d_in[5];
    const float* bi_   = (const float*)d_in[6];
    const float* Wg    = (const float*)d_in[7];
    const float* bg_   = (const float*)d_in[8];
    const float* Wo    = (const float*)d_in[9];
    const float* bo_   = (const float*)d_in[10];
    const float* Wout  = (const float*)d_in[11];
    const float* bout  = (const float*)d_in[12];
    float* out = (float*)d_out;
    ushort* e_ws = (ushort*)d_ws;   // [T][B][24] bf16, ~96 MB

    int nrows = BATCH * T_STEPS;
    emb_kernel<<<nrows / 256, 256, 0, stream>>>(x, Wemb, bemb, e_ws);
    lstm_kernel<<<BATCH / ROWS, 512, 0, stream>>>(e_ws, Wf, bf_, Wi, bi_, Wg, bg_,
                                                  Wo, bo_, Wout, bout, out);
}

// Round 7
// 1447.115 us; speedup vs baseline: 1.3174x; 1.0084x over previous
//
#include <hip/hip_runtime.h>
#include <hip/hip_bf16.h>

#define T_STEPS 2048
#define BATCH   1024
#define NUNITS  128
#define ROWS    8
#define LOG2E   1.4426950408889634f

typedef __attribute__((ext_vector_type(8))) __bf16 bf16x8;
typedef __attribute__((ext_vector_type(4))) float  f32x4;
typedef __attribute__((ext_vector_type(2))) int    i32x2;

__device__ __forceinline__ float sigm_pre(float xs) {
    // xs PRE-SCALED by log2e: sigm = 1/(1+2^-xs)
    return __builtin_amdgcn_rcpf(1.0f + __builtin_amdgcn_exp2f(-xs));
}
__device__ __forceinline__ float tanh_pre(float xs) {
    // xs PRE-SCALED by 2*log2e: tanh = 1 - 2/(1+2^xs); inf-safe (rcp(inf)=0)
    return fmaf(-2.0f, __builtin_amdgcn_rcpf(1.0f + __builtin_amdgcn_exp2f(xs)), 1.0f);
}
// a' = {a.lanes[0:32), b.lanes[0:32)} : VALU-pipe cross-lane (v_permlane32_swap_b32)
__device__ __forceinline__ float swap_lo(float a, float b) {
    i32x2 r = __builtin_amdgcn_permlane32_swap(__builtin_bit_cast(int, a),
                                               __builtin_bit_cast(int, b),
                                               false, false);
    return __builtin_bit_cast(float, r[0]);
}

// ---------------- embedding pre-pass (HBM-bound)
__global__ __launch_bounds__(256) void emb_kernel(const float* __restrict__ x,
                                                  const float* __restrict__ Wemb,
                                                  const float* __restrict__ bemb,
                                                  ushort* __restrict__ e_out) {
    int g = blockIdx.x * 256 + threadIdx.x;   // g = t*1024 + b
    int t = g >> 10;
    int b = g & 1023;
    const float* xr = x + ((size_t)b * T_STEPS + t) * 64;

    float4 xv[16];
#pragma unroll
    for (int i = 0; i < 16; i++) xv[i] = ((const float4*)xr)[i];

    float acc[24];
#pragma unroll
    for (int j = 0; j < 24; j++) acc[j] = bemb[j];

#pragma unroll
    for (int d = 0; d < 64; d++) {
        float xs = ((const float*)xv)[d];
#pragma unroll
        for (int j = 0; j < 24; j++) acc[j] = fmaf(xs, Wemb[d * 24 + j], acc[j]);
    }

    uint outp[12];
#pragma unroll
    for (int p = 0; p < 12; p++) {
        float lo = __builtin_amdgcn_rcpf(1.0f + __builtin_amdgcn_exp2f(-LOG2E * acc[2 * p]));
        float hi = __builtin_amdgcn_rcpf(1.0f + __builtin_amdgcn_exp2f(-LOG2E * acc[2 * p + 1]));
        ushort ulo = __builtin_bit_cast(ushort, (__bf16)lo);
        ushort uhi = __builtin_bit_cast(ushort, (__bf16)hi);
        outp[p] = (uint)ulo | ((uint)uhi << 16);
    }
    uint4* dst = (uint4*)(e_out + (size_t)g * 24);
#pragma unroll
    for (int q = 0; q < 3; q++) dst[q] = ((const uint4*)outp)[q];
}

// ---------------- recurrent kernel: 128 blocks x 512 threads (8 waves), 8 rows/block
// A = z (LDS), B = W (regs): D[m=batchrow][n=unit]; lane(kg,l15) reg r ->
// row kg*4+r, unit 16wv+l15. Valid rows (<8) live in lanes 0-31 (kg<2).
// Compaction: lanes 32-63 take regs{2,3} from lane-32 via permlane32_swap (VALU pipe,
// replaces R6's bpermutes on the contended LDS pipe).
// Thread's 2 cells: rows [0,4,2,6][lane>>4] + {0,1}, unit = 16wv + (lane&15).
__global__ __launch_bounds__(512, 1) void lstm_kernel(
    const ushort* __restrict__ e_ws,
    const float* __restrict__ Wf, const float* __restrict__ bf_,
    const float* __restrict__ Wi, const float* __restrict__ bi_,
    const float* __restrict__ Wg, const float* __restrict__ bg_,
    const float* __restrict__ Wo, const float* __restrict__ bo_,
    const float* __restrict__ Wout, const float* __restrict__ bout,
    float* __restrict__ out) {
    __shared__ __align__(16) __bf16 zfrag[2][4][4][16][8];   // [P][ks][kslot][row16][8] = 8 KiB

    const int tid  = threadIdx.x;
    const int lane = tid & 63;
    const int wv   = tid >> 6;      // 0..7 -> unit tile [16wv,16wv+16)
    const int l15  = lane & 15;
    const int kg   = lane >> 4;     // 0..3 (A/B k-group; also D row-group)
    const int r0   = blockIdx.x * ROWS;

    // ---- persistent W fragments wreg[gate][ks] (B operand: n=l15, k=kg*8+j+32ks),
    // pre-scaled by the exp2 constants
    const float* Wp[4] = {Wf, Wi, Wg, Wo};
    const float gsc[4] = {LOG2E, LOG2E, 2.0f * LOG2E, LOG2E};
    const int ucol = wv * 16 + l15;   // this lane's unit (D n-index)
    bf16x8 wreg[4][5];
#pragma unroll
    for (int gt = 0; gt < 4; gt++) {
#pragma unroll
        for (int ks = 0; ks < 5; ks++) {
#pragma unroll
            for (int j = 0; j < 8; j++) {
                int k = ks * 32 + kg * 8 + j;
                float v = 0.0f;
                if (k < 128) v = Wp[gt][(24 + k) * NUNITS + ucol];        // h rows
                else if (k < 152) v = Wp[gt][(k - 128) * NUNITS + ucol];  // e rows
                wreg[gt][ks][j] = (__bf16)(v * gsc[gt]);
            }
        }
    }
    // bias: D/C cell (m,n) needs bias[unit = n = l15-based] -> per-lane SPLAT
    const float* Bp[4] = {bf_, bi_, bg_, bo_};
    f32x4 bias[4];
#pragma unroll
    for (int gt = 0; gt < 4; gt++) {
        float bv = Bp[gt][ucol] * gsc[gt];
#pragma unroll
        for (int r = 0; r < 4; r++) bias[gt][r] = bv;
    }

    // zero both z buffers (h0 = 0; rows 8-15 stay zero forever)
    for (int i = tid; i < 2 * 4 * 4 * 16 * 8; i += 512) ((__bf16*)zfrag)[i] = (__bf16)0.0f;

    // LDS addresses; [P] stride = 2048 elems, [ks] stride = 512
    // A-frag read: z[row=l15][k = kg*8+j + 32ks] -> same addresses as R6
    const __bf16* zrd = &zfrag[0][0][kg][l15][0];
    // write slots: 2 cells (row_c0, ucol), (row_c0+1, ucol); row stride = 8 elems
    const int q2 = lane >> 4;
    const int row_c0 = ((q2 & 1) << 2) | ((q2 >> 1) << 1);   // [0,4,2,6][q2]
    __bf16* zwr = &zfrag[0][ucol >> 5][(ucol >> 3) & 3][row_c0][ucol & 7];

    // ---- e prefetch ring, depth 2 (A rows l15<8, k-groups kg<3)
    const ushort* elbase = e_ws + ((size_t)(r0 + (l15 & 7)) * 24 + kg * 8);
    const bool eload = (kg < 3) && (l15 < 8);
    bf16x8 e0, e1;
#pragma unroll
    for (int j = 0; j < 8; j++) { e0[j] = (__bf16)0.0f; e1[j] = (__bf16)0.0f; }
    if (eload) {
        e0 = *(const bf16x8*)(const void*)(elbase);
        e1 = *(const bf16x8*)(const void*)(elbase + 24576);   // t=1
    }

    __syncthreads();

    float c0 = 0.0f, c1 = 0.0f;   // cell state for this thread's 2 cells
    f32x4 eA[4], eB[4];           // hoisted e-acc (bias + W_e*e(t)) per gate
#pragma unroll
    for (int gt = 0; gt < 4; gt++)
        eA[gt] = __builtin_amdgcn_mfma_f32_16x16x32_bf16(e0, wreg[gt][4], bias[gt], 0, 0, 0);
    if (eload) e0 = *(const bf16x8*)(const void*)(elbase + 2 * 24576);   // e(2)

    auto STEP = [&](int t, int P, f32x4 (&cur)[4], f32x4 (&nxt)[4], bf16x8& enext) {
        const __bf16* zb = zrd + P * 2048;
        bf16x8 z0 = *(const bf16x8*)(const void*)(zb);
        bf16x8 z1 = *(const bf16x8*)(const void*)(zb + 512);
        bf16x8 z2 = *(const bf16x8*)(const void*)(zb + 1024);
        bf16x8 z3 = *(const bf16x8*)(const void*)(zb + 1536);

        f32x4 acc[4];
#pragma unroll
        for (int gt = 0; gt < 4; gt++) {
            acc[gt] = __builtin_amdgcn_mfma_f32_16x16x32_bf16(z0, wreg[gt][0], cur[gt], 0, 0, 0);
            acc[gt] = __builtin_amdgcn_mfma_f32_16x16x32_bf16(z1, wreg[gt][1], acc[gt], 0, 0, 0);
            acc[gt] = __builtin_amdgcn_mfma_f32_16x16x32_bf16(z2, wreg[gt][2], acc[gt], 0, 0, 0);
            acc[gt] = __builtin_amdgcn_mfma_f32_16x16x32_bf16(z3, wreg[gt][3], acc[gt], 0, 0, 0);
        }

        // hoisted e-MFMAs for step t+1 (independent of h)
#pragma unroll
        for (int gt = 0; gt < 4; gt++)
            nxt[gt] = __builtin_amdgcn_mfma_f32_16x16x32_bf16(enext, wreg[gt][4], bias[gt], 0, 0, 0);
        {
            int tf = t + 3; if (tf > T_STEPS - 1) tf = T_STEPS - 1;
            if (eload) enext = *(const bf16x8*)(const void*)(elbase + (size_t)tf * 24576);
        }

        // compaction on the VALU pipe: lanes<32 keep regs{0,1} (rows 0/4),
        // lanes>=32 receive regs{2,3} of lane-32 (rows 2/6)
        float g0[4], g1[4];
#pragma unroll
        for (int gt = 0; gt < 4; gt++) {
            g0[gt] = swap_lo(acc[gt][0], acc[gt][2]);
            g1[gt] = swap_lo(acc[gt][1], acc[gt][3]);
        }

        float fg0 = sigm_pre(g0[0]), fg1 = sigm_pre(g1[0]);
        float ig0 = sigm_pre(g0[1]), ig1 = sigm_pre(g1[1]);
        float gg0 = tanh_pre(g0[2]), gg1 = tanh_pre(g1[2]);
        float og0 = sigm_pre(g0[3]), og1 = sigm_pre(g1[3]);
        c0 = fmaf(c0, fg0, ig0 * gg0);
        c1 = fmaf(c1, fg1, ig1 * gg1);
        float h0 = tanh_pre(2.0f * LOG2E * c0) * og0;
        float h1 = tanh_pre(2.0f * LOG2E * c1) * og1;

        __bf16* zw = zwr + (P ^ 1) * 2048;
        zw[0] = (__bf16)h0;       // (row_c0,   unit)
        zw[8] = (__bf16)h1;       // (row_c0+1, unit)

        // LDS-only drain + raw barrier: vmem e-prefetch stays in flight
        asm volatile("s_waitcnt lgkmcnt(0)" ::: "memory");
        __builtin_amdgcn_s_barrier();
        __builtin_amdgcn_sched_barrier(0);
    };

    for (int t = 0; t < T_STEPS; t += 2) {
        STEP(t,     0, eA, eB, e1);
        STEP(t + 1, 1, eB, eA, e0);
    }

    // h_last is in buffer 0
    if (tid < ROWS) {
        float s = bout[0];
#pragma unroll
        for (int k = 0; k < NUNITS; k++)
            s += (float)zfrag[0][k >> 5][(k >> 3) & 3][tid][k & 7] * Wout[k];
        out[r0 + tid] = __builtin_amdgcn_rcpf(1.0f + __builtin_amdgcn_exp2f(-LOG2E * s));
    }
}

extern "C" void kernel_launch(void* const* d_in, const int* in_sizes, int n_in,
                              void* d_out, int out_size, void* d_ws, size_t ws_size,
                              hipStream_t stream) {
    const float* x     = (const float*)d_in[0];
    const float* Wemb  = (const float*)d_in[1];
    const float* bemb  = (const float*)d_in[2];
    const float* Wf    = (const float*)d_in[3];
    const float* bf_   = (const float*)d_in[4];
    const float* Wi    = (const float*)d_in[5];
    const float* bi_   = (const float*)d_in[6];
    const float* Wg    = (const float*)d_in[7];
    const float* bg_   = (const float*)d_in[8];
    const float* Wo    = (const float*)d_in[9];
    const float* bo_   = (const float*)d_in[10];
    const float* Wout  = (const float*)d_in[11];
    const float* bout  = (const float*)d_in[12];
    float* out = (float*)d_out;
    ushort* e_ws = (ushort*)d_ws;   // [T][B][24] bf16, ~96 MB

    int nrows = BATCH * T_STEPS;
    emb_kernel<<<nrows / 256, 256, 0, stream>>>(x, Wemb, bemb, e_ws);
    lstm_kernel<<<BATCH / ROWS, 512, 0, stream>>>(e_ws, Wf, bf_, Wi, bi_, Wg, bg_,
                                                  Wo, bo_, Wout, bout, out);
}